// Round 1
// baseline (340.302 us; speedup 1.0000x reference)
//
#include <hip/hip_runtime.h>
#include <hip/hip_bf16.h>

typedef unsigned short u16;
typedef __attribute__((ext_vector_type(8))) short short8;
typedef __attribute__((ext_vector_type(8))) u16 u16x8;
typedef __attribute__((ext_vector_type(4))) u16 u16x4;
typedef __attribute__((ext_vector_type(4))) float f32x4;

__device__ __forceinline__ u16 f2bf(float f) {
  __hip_bfloat16 h = __float2bfloat16(f);
  u16 u;
  __builtin_memcpy(&u, &h, 2);
  return u;
}

__device__ __forceinline__ f32x4 mfma16(short8 a, short8 b, f32x4 c) {
  return __builtin_amdgcn_mfma_f32_16x16x32_bf16(a, b, c, 0, 0, 0);
}

__device__ __forceinline__ void gl_lds16(const void* g, void* l) {
  __builtin_amdgcn_global_load_lds(
      (const __attribute__((address_space(1))) unsigned int*)g,
      (__attribute__((address_space(3))) unsigned int*)l, 16, 0, 0);
}

// ---------------- convert x fp32 -> bf16 ----------------
__global__ __launch_bounds__(256) void cvt_x_k(const float* __restrict__ x,
                                               u16* __restrict__ xb) {
  int i = (blockIdx.x * 256 + threadIdx.x) * 4;
  float4 v = *(const float4*)(x + i);
  u16x4 o = { f2bf(v.x), f2bf(v.y), f2bf(v.z), f2bf(v.w) };
  *(u16x4*)(xb + i) = o;
}

// ---------------- transpose + convert weight: wt[n][k] = w[k][n], K=768 ----
__global__ __launch_bounds__(256) void cvt_wt_k(const float* __restrict__ w,
                                                u16* __restrict__ wt, int N) {
  int i = blockIdx.x * 256 + threadIdx.x;  // over N*768
  int nn = i / 768, kk = i % 768;
  wt[i] = f2bf(w[(size_t)kk * N + nn]);
}

// ---------------- CPB bias MLP: 729 entries x (2->512->24), 16*sigmoid -----
__device__ __forceinline__ float cpb_coord(int v) {
  float c = (float)(v - 13) * (8.0f / 13.0f);
  float a = fabsf(c);
  float r = log2f(a + 1.0f) * (1.0f / 3.0f);
  return c < 0.f ? -r : r;
}

__global__ __launch_bounds__(64) void bias_mlp_k(
    const float* __restrict__ w1, const float* __restrict__ b1,
    const float* __restrict__ w2, const float* __restrict__ b2,
    float* __restrict__ btab) {
  int e = blockIdx.x;
  int lane = threadIdx.x;
  float t0 = cpb_coord(e / 27), t1 = cpb_coord(e % 27);
  float acc[24];
#pragma unroll
  for (int hh = 0; hh < 24; hh++) acc[hh] = 0.f;
#pragma unroll
  for (int jj = 0; jj < 8; jj++) {
    int j = lane * 8 + jj;
    float h1 = t0 * w1[j] + t1 * w1[512 + j] + b1[j];
    h1 = fmaxf(h1, 0.f);
#pragma unroll
    for (int hh = 0; hh < 24; hh++) acc[hh] += h1 * w2[j * 24 + hh];
  }
#pragma unroll
  for (int hh = 0; hh < 24; hh++)
#pragma unroll
    for (int m = 1; m < 64; m <<= 1) acc[hh] += __shfl_xor(acc[hh], m, 64);
  if (lane == 0) {
#pragma unroll
    for (int hh = 0; hh < 24; hh++) {
      float v = acc[hh] + b2[hh];
      btab[e * 24 + hh] = 16.f / (1.f + __expf(-v));
    }
  }
}

// ---------------- expand bias to [24][196][208] fp32 ----------------------
__global__ __launch_bounds__(256) void bias_expand_k(const float* __restrict__ tab,
                                                     float* __restrict__ be) {
  int i = blockIdx.x * 256 + threadIdx.x;  // 24*196*208
  int h = i / (196 * 208);
  int rem = i % (196 * 208);
  int row = rem / 208, col = rem % 208;
  float v = 0.f;
  if (col < 196) {
    int dy = row / 14 - col / 14 + 13;
    int dx = row % 14 - col % 14 + 13;
    v = tab[(dy * 27 + dx) * 24 + h];
  }
  be[i] = v;
}

// ---------------- GEMM: C = A[M][K] * Bt[N][K]^T + bias -------------------
// EPI=0: scatter to q/k/v bf16 [B][H][196][32].  EPI=1: fp32 row-major out.
template <int EPI>
__global__ __launch_bounds__(256) void gemm_k(
    const u16* __restrict__ A, const u16* __restrict__ Bt,
    const float* __restrict__ bias, float* __restrict__ Cf,
    u16* __restrict__ qo, u16* __restrict__ ko, u16* __restrict__ vo,
    int N, int K) {
  __shared__ u16 As[128 * 32];
  __shared__ u16 Bs[128 * 32];
  const int tid = threadIdx.x, lane = tid & 63, w = tid >> 6;
  const int r16 = lane & 15, q4 = lane >> 4;
  const int wr = w >> 1, wc = w & 1;
  const int m0 = blockIdx.y * 128, n0 = blockIdx.x * 128;
  const int ksw = (q4 ^ ((r16 >> 1) & 3)) * 16;  // swizzled chunk byte offset

  f32x4 acc[4][4] = {};

  for (int k0 = 0; k0 < K; k0 += 32) {
#pragma unroll
    for (int gg = 0; gg < 2; gg++) {
      int g = w * 2 + gg;
      int chunk = g * 64 + lane;
      int row = chunk >> 2;
      int gch = (chunk & 3) ^ ((row >> 1) & 3);
      gl_lds16(A + (size_t)(m0 + row) * K + k0 + gch * 8, (char*)As + g * 1024);
      gl_lds16(Bt + (size_t)(n0 + row) * K + k0 + gch * 8, (char*)Bs + g * 1024);
    }
    __syncthreads();
    short8 af[4], bfr[4];
#pragma unroll
    for (int i = 0; i < 4; i++)
      af[i] = *(const short8*)((const char*)As + (wr * 64 + i * 16 + r16) * 64 + ksw);
#pragma unroll
    for (int j = 0; j < 4; j++)
      bfr[j] = *(const short8*)((const char*)Bs + (wc * 64 + j * 16 + r16) * 64 + ksw);
#pragma unroll
    for (int i = 0; i < 4; i++)
#pragma unroll
      for (int j = 0; j < 4; j++) acc[i][j] = mfma16(af[i], bfr[j], acc[i][j]);
    __syncthreads();
  }

  if (EPI == 1) {
#pragma unroll
    for (int i = 0; i < 4; i++) {
#pragma unroll
      for (int r = 0; r < 4; r++) {
        int m = m0 + wr * 64 + i * 16 + q4 * 4 + r;
#pragma unroll
        for (int j = 0; j < 4; j++) {
          int n = n0 + wc * 64 + j * 16 + r16;
          Cf[(size_t)m * N + n] = acc[i][j][r] + bias[n];
        }
      }
    }
  } else {
#pragma unroll
    for (int j = 0; j < 4; j++) {
      int n = n0 + wc * 64 + j * 16 + r16;
      int s = n / 768, rem = n % 768;
      int hh = rem >> 5, d = rem & 31;
      u16* dst = (s == 0) ? qo : ((s == 1) ? ko : vo);
      float bn = bias[n];
#pragma unroll
      for (int i = 0; i < 4; i++) {
#pragma unroll
        for (int r = 0; r < 4; r++) {
          int m = m0 + wr * 64 + i * 16 + q4 * 4 + r;
          int bb = m / 196, tok = m % 196;
          dst[((bb * 24 + hh) * 196 + tok) * 32 + d] = f2bf(acc[i][j][r] + bn);
        }
      }
    }
  }
}

// ---------------- attention: one block per (b,h) --------------------------
__global__ __launch_bounds__(256) void attn_k(
    const u16* __restrict__ q_ws, const u16* __restrict__ k_ws,
    const u16* __restrict__ v_ws, const float* __restrict__ be,
    u16* __restrict__ ao) {
  constexpr int PST = 232, VST = 232;
  __shared__ u16 Ks[208 * 32];       // swizzled chunks, rows 0..207
  __shared__ u16 Vt[32 * VST];       // V transposed: Vt[d][n]
  __shared__ u16 Ps[4][16 * PST];    // per-wave P strip
  const int tid = threadIdx.x, lane = tid & 63, w = tid >> 6;
  const int r16 = lane & 15, q4 = lane >> 4;
  const int bh = blockIdx.x, b = bh / 24, h = bh % 24;
  const u16* qp = q_ws + (size_t)bh * 6272;
  const u16* kp = k_ws + (size_t)bh * 6272;
  const u16* vp = v_ws + (size_t)bh * 6272;
  const float* bp = be + h * (196 * 208);
  const int ksw = (q4 ^ ((r16 >> 1) & 3)) * 16;

  // stage K rows 0..207 (832 chunks = 13 wave-groups), swizzled source
  for (int g = w; g < 13; g += 4) {
    int chunk = g * 64 + lane;
    int row = chunk >> 2;
    int gch = (chunk & 3) ^ ((row >> 1) & 3);
    gl_lds16(kp + row * 32 + gch * 8, (char*)Ks + g * 1024);
  }
  // stage V transposed
  for (int c = tid; c < 784; c += 256) {
    int n = c >> 2, d0 = (c & 3) * 8;
    u16x8 vv = *(const u16x8*)(vp + c * 8);
#pragma unroll
    for (int jj = 0; jj < 8; jj++) Vt[(d0 + jj) * VST + n] = vv[jj];
  }
  // zero Vt pad cols 196..231
  for (int idx = tid; idx < 32 * 36; idx += 256) {
    int d = idx / 36, n = 196 + idx % 36;
    Vt[d * VST + n] = 0;
  }
  // zero Ps pad cols 208..231 (per wave)
  for (int idx = lane; idx < 16 * 24; idx += 64) {
    int row = idx / 24, col = 208 + idx % 24;
    Ps[w][row * PST + col] = 0;
  }
  __syncthreads();

  f32x4 z = {0.f, 0.f, 0.f, 0.f};
  for (int si = w; si < 13; si += 4) {
    // Q A-frag straight from global (each row read exactly once)
    short8 aq = *(const short8*)(qp + (si * 16 + r16) * 32 + q4 * 8);
    f32x4 acc[13];
#pragma unroll
    for (int t = 0; t < 13; t++) {
      short8 bk = *(const short8*)((const char*)Ks + (t * 16 + r16) * 64 + ksw);
      acc[t] = mfma16(aq, bk, z);
    }
    // bias + mask + row max
    float mx[4] = {-3e38f, -3e38f, -3e38f, -3e38f};
#pragma unroll
    for (int t = 0; t < 13; t++) {
      int col = t * 16 + r16;
#pragma unroll
      for (int r = 0; r < 4; r++) {
        int grow = si * 16 + q4 * 4 + r;
        int gc = grow < 196 ? grow : 195;
        float s = acc[t][r] * 0.17677669529663687f + bp[gc * 208 + col];
        s = (col < 196) ? s : -3e38f;
        acc[t][r] = s;
        mx[r] = fmaxf(mx[r], s);
      }
    }
#pragma unroll
    for (int r = 0; r < 4; r++)
#pragma unroll
      for (int m = 1; m < 16; m <<= 1) mx[r] = fmaxf(mx[r], __shfl_xor(mx[r], m, 64));
    float sum[4] = {0.f, 0.f, 0.f, 0.f};
#pragma unroll
    for (int t = 0; t < 13; t++)
#pragma unroll
      for (int r = 0; r < 4; r++) {
        float p = __expf(acc[t][r] - mx[r]);
        acc[t][r] = p;
        sum[r] += p;
      }
#pragma unroll
    for (int r = 0; r < 4; r++) {
#pragma unroll
      for (int m = 1; m < 16; m <<= 1) sum[r] += __shfl_xor(sum[r], m, 64);
      sum[r] = 1.0f / sum[r];
    }
    // P -> LDS (bf16)
#pragma unroll
    for (int t = 0; t < 13; t++) {
      int col = t * 16 + r16;
#pragma unroll
      for (int r = 0; r < 4; r++)
        Ps[w][(q4 * 4 + r) * PST + col] = f2bf(acc[t][r] * sum[r]);
    }
    // PV: 7 k-tiles of 32
    f32x4 o0 = z, o1 = z;
#pragma unroll
    for (int t = 0; t < 7; t++) {
      short8 ap = *(const short8*)(&Ps[w][r16 * PST + t * 32 + q4 * 8]);
      short8 b0 = *(const short8*)(&Vt[r16 * VST + t * 32 + q4 * 8]);
      short8 b1 = *(const short8*)(&Vt[(16 + r16) * VST + t * 32 + q4 * 8]);
      o0 = mfma16(ap, b0, o0);
      o1 = mfma16(ap, b1, o1);
    }
    // write O (bf16) to attnout[b][n][h*32+d]
#pragma unroll
    for (int r = 0; r < 4; r++) {
      int grow = si * 16 + q4 * 4 + r;
      if (grow < 196) {
        u16* op = ao + ((size_t)(b * 196 + grow)) * 768 + h * 32;
        op[r16] = f2bf(o0[r]);
        op[16 + r16] = f2bf(o1[r]);
      }
    }
  }
}

// ---------------------------------------------------------------------------
extern "C" void kernel_launch(void* const* d_in, const int* in_sizes, int n_in,
                              void* d_out, int out_size, void* d_ws, size_t ws_size,
                              hipStream_t stream) {
  const float* x = (const float*)d_in[0];
  const float* qkv_w = (const float*)d_in[1];
  const float* qkv_b = (const float*)d_in[2];
  const float* proj_w = (const float*)d_in[3];
  const float* proj_b = (const float*)d_in[4];
  const float* cpb_w1 = (const float*)d_in[5];
  const float* cpb_b1 = (const float*)d_in[6];
  const float* cpb_w2 = (const float*)d_in[7];
  const float* cpb_b2 = (const float*)d_in[8];
  float* out = (float*)d_out;

  char* ws = (char*)d_ws;
  size_t o = 0;
  auto alloc = [&](size_t sz) {
    size_t r = o;
    o = (o + sz + 255) & ~(size_t)255;
    return r;
  };
  const size_t ME = (size_t)25088 * 768;  // elems per [B,N,DIM]-sized tensor
  u16* x_bf = (u16*)(ws + alloc(ME * 2));           // also aliased as attnout
  u16* wq_t = (u16*)(ws + alloc((size_t)2304 * 768 * 2));
  u16* wp_t = (u16*)(ws + alloc((size_t)768 * 768 * 2));
  u16* qkv_s = (u16*)(ws + alloc(3 * ME * 2));      // q,k,v contiguous
  float* btab = (float*)(ws + alloc((size_t)729 * 24 * 4));
  float* bexp = (float*)(ws + alloc((size_t)24 * 196 * 208 * 4));
  u16* q_ws = qkv_s;
  u16* k_ws = qkv_s + ME;
  u16* v_ws = k_ws + ME;
  u16* ao = x_bf;  // alias: x_bf dead after qkv GEMM

  cvt_x_k<<<18816, 256, 0, stream>>>(x, x_bf);
  cvt_wt_k<<<6912, 256, 0, stream>>>(qkv_w, wq_t, 2304);
  cvt_wt_k<<<2304, 256, 0, stream>>>(proj_w, wp_t, 768);
  bias_mlp_k<<<729, 64, 0, stream>>>(cpb_w1, cpb_b1, cpb_w2, cpb_b2, btab);
  bias_expand_k<<<3822, 256, 0, stream>>>(btab, bexp);
  gemm_k<0><<<dim3(18, 196), 256, 0, stream>>>(x_bf, wq_t, qkv_b, nullptr,
                                               q_ws, k_ws, v_ws, 2304, 768);
  attn_k<<<3072, 256, 0, stream>>>(q_ws, k_ws, v_ws, bexp, ao);
  gemm_k<1><<<dim3(6, 196), 256, 0, stream>>>(ao, wp_t, proj_b, out,
                                              nullptr, nullptr, nullptr, 768, 768);
}

// Round 2
// 314.725 us; speedup vs baseline: 1.0813x; 1.0813x over previous
//
#include <hip/hip_runtime.h>
#include <hip/hip_bf16.h>

typedef unsigned short u16;
typedef __attribute__((ext_vector_type(8))) short short8;
typedef __attribute__((ext_vector_type(8))) u16 u16x8;
typedef __attribute__((ext_vector_type(4))) u16 u16x4;
typedef __attribute__((ext_vector_type(4))) float f32x4;

__device__ __forceinline__ u16 f2bf(float f) {
  __hip_bfloat16 h = __float2bfloat16(f);
  u16 u;
  __builtin_memcpy(&u, &h, 2);
  return u;
}

__device__ __forceinline__ f32x4 mfma16(short8 a, short8 b, f32x4 c) {
  return __builtin_amdgcn_mfma_f32_16x16x32_bf16(a, b, c, 0, 0, 0);
}

__device__ __forceinline__ void gl_lds16(const void* g, void* l) {
  __builtin_amdgcn_global_load_lds(
      (const __attribute__((address_space(1))) unsigned int*)g,
      (__attribute__((address_space(3))) unsigned int*)l, 16, 0, 0);
}

// ---------------- convert x fp32 -> bf16 ----------------
__global__ __launch_bounds__(256) void cvt_x_k(const float* __restrict__ x,
                                               u16* __restrict__ xb) {
  int i = (blockIdx.x * 256 + threadIdx.x) * 4;
  float4 v = *(const float4*)(x + i);
  u16x4 o = { f2bf(v.x), f2bf(v.y), f2bf(v.z), f2bf(v.w) };
  *(u16x4*)(xb + i) = o;
}

// ---------------- transpose + convert weight: wt[n][k] = w[k][n], K=768 ----
__global__ __launch_bounds__(256) void cvt_wt_k(const float* __restrict__ w,
                                                u16* __restrict__ wt, int N) {
  int i = blockIdx.x * 256 + threadIdx.x;  // over N*768
  int nn = i / 768, kk = i % 768;
  wt[i] = f2bf(w[(size_t)kk * N + nn]);
}

// ---------------- CPB bias MLP: 729 entries x (2->512->24), 16*sigmoid -----
__device__ __forceinline__ float cpb_coord(int v) {
  float c = (float)(v - 13) * (8.0f / 13.0f);
  float a = fabsf(c);
  float r = log2f(a + 1.0f) * (1.0f / 3.0f);
  return c < 0.f ? -r : r;
}

__global__ __launch_bounds__(64) void bias_mlp_k(
    const float* __restrict__ w1, const float* __restrict__ b1,
    const float* __restrict__ w2, const float* __restrict__ b2,
    float* __restrict__ btab) {
  int e = blockIdx.x;
  int lane = threadIdx.x;
  float t0 = cpb_coord(e / 27), t1 = cpb_coord(e % 27);
  float acc[24];
#pragma unroll
  for (int hh = 0; hh < 24; hh++) acc[hh] = 0.f;
#pragma unroll
  for (int jj = 0; jj < 8; jj++) {
    int j = lane * 8 + jj;
    float h1 = t0 * w1[j] + t1 * w1[512 + j] + b1[j];
    h1 = fmaxf(h1, 0.f);
#pragma unroll
    for (int hh = 0; hh < 24; hh++) acc[hh] += h1 * w2[j * 24 + hh];
  }
#pragma unroll
  for (int hh = 0; hh < 24; hh++)
#pragma unroll
    for (int m = 1; m < 64; m <<= 1) acc[hh] += __shfl_xor(acc[hh], m, 64);
  if (lane == 0) {
#pragma unroll
    for (int hh = 0; hh < 24; hh++) {
      float v = acc[hh] + b2[hh];
      btab[e * 24 + hh] = 16.f / (1.f + __expf(-v));
    }
  }
}

// ---------------- expand bias to [24][196][208] fp32 ----------------------
__global__ __launch_bounds__(256) void bias_expand_k(const float* __restrict__ tab,
                                                     float* __restrict__ be) {
  int i = blockIdx.x * 256 + threadIdx.x;  // 24*196*208
  int h = i / (196 * 208);
  int rem = i % (196 * 208);
  int row = rem / 208, col = rem % 208;
  float v = 0.f;
  if (col < 196) {
    int dy = row / 14 - col / 14 + 13;
    int dx = row % 14 - col % 14 + 13;
    v = tab[(dy * 27 + dx) * 24 + h];
  }
  be[i] = v;
}

// ---------------- GEMM: C = A[M][K] * Bt[N][K]^T + bias -------------------
// Natural row-major output. EPI=0: bf16 to Cb. EPI=1: fp32 to Cf.
// BK=64, chunk-XOR LDS swizzle, XCD-chunked block swizzle (nwg % 8 == 0).
template <int EPI>
__global__ __launch_bounds__(256) void gemm_k(
    const u16* __restrict__ A, const u16* __restrict__ Bt,
    const float* __restrict__ bias, float* __restrict__ Cf,
    u16* __restrict__ Cb, int N, int K, int nbx) {
  __shared__ u16 As[128 * 64];
  __shared__ u16 Bs[128 * 64];
  const int tid = threadIdx.x, lane = tid & 63, w = tid >> 6;
  const int r16 = lane & 15, q4 = lane >> 4;
  const int wr = w >> 1, wc = w & 1;
  // XCD-chunked bijective swizzle: same-m blocks grouped per XCD
  const int nwg = gridDim.x, cpx = nwg >> 3;
  const int swz = (blockIdx.x & 7) * cpx + (blockIdx.x >> 3);
  const int m0 = (swz / nbx) * 128, n0 = (swz % nbx) * 128;

  f32x4 acc[4][4] = {};

  for (int k0 = 0; k0 < K; k0 += 64) {
#pragma unroll
    for (int g = 0; g < 4; g++) {
      int chunk = (w * 4 + g) * 64 + lane;
      int row = chunk >> 3, p = chunk & 7;
      int gch = p ^ (row & 7);
      gl_lds16(A + (size_t)(m0 + row) * K + k0 + gch * 8, (char*)As + (w * 4 + g) * 1024);
      gl_lds16(Bt + (size_t)(n0 + row) * K + k0 + gch * 8, (char*)Bs + (w * 4 + g) * 1024);
    }
    __syncthreads();
#pragma unroll
    for (int kk = 0; kk < 2; kk++) {
      short8 af[4], bfr[4];
#pragma unroll
      for (int i = 0; i < 4; i++) {
        int row = wr * 64 + i * 16 + r16;
        int pc = (kk * 4 + q4) ^ (r16 & 7);
        af[i] = *(const short8*)((const char*)As + row * 128 + pc * 16);
      }
#pragma unroll
      for (int j = 0; j < 4; j++) {
        int row = wc * 64 + j * 16 + r16;
        int pc = (kk * 4 + q4) ^ (r16 & 7);
        bfr[j] = *(const short8*)((const char*)Bs + row * 128 + pc * 16);
      }
#pragma unroll
      for (int i = 0; i < 4; i++)
#pragma unroll
        for (int j = 0; j < 4; j++) acc[i][j] = mfma16(af[i], bfr[j], acc[i][j]);
    }
    __syncthreads();
  }

  // epilogue: natural row-major writes, no div/mod
  const int nb = n0 + wc * 64 + r16;
  float bn[4];
#pragma unroll
  for (int j = 0; j < 4; j++) bn[j] = bias[nb + j * 16];
#pragma unroll
  for (int i = 0; i < 4; i++) {
#pragma unroll
    for (int r = 0; r < 4; r++) {
      int m = m0 + wr * 64 + i * 16 + q4 * 4 + r;
      if (EPI == 1) {
        float* cp = Cf + (size_t)m * N + nb;
#pragma unroll
        for (int j = 0; j < 4; j++) cp[j * 16] = acc[i][j][r] + bn[j];
      } else {
        u16* cp = Cb + (size_t)m * N + nb;
#pragma unroll
        for (int j = 0; j < 4; j++) cp[j * 16] = f2bf(acc[i][j][r] + bn[j]);
      }
    }
  }
}

// ---------------- attention: one block per (b,h) --------------------------
// q/k/v live in qkv[25088][2304]: q at col h*32, k at 768+h*32, v at 1536+h*32
__global__ __launch_bounds__(256) void attn_k(
    const u16* __restrict__ qkv, const float* __restrict__ be,
    u16* __restrict__ ao) {
  constexpr int PST = 232, VST = 232;
  __shared__ u16 Ks[208 * 32];       // swizzled chunks, rows 0..207
  __shared__ u16 Vt[32 * VST];       // V transposed: Vt[d][n]
  __shared__ u16 Ps[4][16 * PST];    // per-wave P strip
  const int tid = threadIdx.x, lane = tid & 63, w = tid >> 6;
  const int r16 = lane & 15, q4 = lane >> 4;
  const int bh = blockIdx.x, b = bh / 24, h = bh % 24;
  const u16* qp = qkv + (size_t)(b * 196) * 2304 + h * 32;
  const u16* kp = qp + 768;
  const u16* vp = qp + 1536;
  const float* bp = be + h * (196 * 208);
  const int ksw = (q4 ^ ((r16 >> 1) & 3)) * 16;

  // stage K rows 0..207 (832 chunks = 13 wave-groups), swizzled source
  // rows >=196 read past this (b,h) region: garbage, masked later (ws-safe)
  for (int g = w; g < 13; g += 4) {
    int chunk = g * 64 + lane;
    int row = chunk >> 2;
    int gch = (chunk & 3) ^ ((row >> 1) & 3);
    gl_lds16(kp + (size_t)row * 2304 + gch * 8, (char*)Ks + g * 1024);
  }
  // stage V transposed
  for (int c = tid; c < 784; c += 256) {
    int n = c >> 2, d0 = (c & 3) * 8;
    u16x8 vv = *(const u16x8*)(vp + (size_t)n * 2304 + (c & 3) * 8);
#pragma unroll
    for (int jj = 0; jj < 8; jj++) Vt[(d0 + jj) * VST + n] = vv[jj];
  }
  // zero Vt pad cols 196..231
  for (int idx = tid; idx < 32 * 36; idx += 256) {
    int d = idx / 36, n = 196 + idx % 36;
    Vt[d * VST + n] = 0;
  }
  // zero Ps pad cols 208..231 (per wave)
  for (int idx = lane; idx < 16 * 24; idx += 64) {
    int row = idx / 24, col = 208 + idx % 24;
    Ps[w][row * PST + col] = 0;
  }
  __syncthreads();

  f32x4 z = {0.f, 0.f, 0.f, 0.f};
  for (int si = w; si < 13; si += 4) {
    // Q A-frag straight from global (each row read exactly once)
    short8 aq = *(const short8*)(qp + (size_t)(si * 16 + r16) * 2304 + q4 * 8);
    f32x4 acc[13];
#pragma unroll
    for (int t = 0; t < 13; t++) {
      short8 bk = *(const short8*)((const char*)Ks + (t * 16 + r16) * 64 + ksw);
      acc[t] = mfma16(aq, bk, z);
    }
    // bias + mask + row max
    float mx[4] = {-3e38f, -3e38f, -3e38f, -3e38f};
#pragma unroll
    for (int t = 0; t < 13; t++) {
      int col = t * 16 + r16;
#pragma unroll
      for (int r = 0; r < 4; r++) {
        int grow = si * 16 + q4 * 4 + r;
        int gc = grow < 196 ? grow : 195;
        float s = acc[t][r] * 0.17677669529663687f + bp[gc * 208 + col];
        s = (col < 196) ? s : -3e38f;
        acc[t][r] = s;
        mx[r] = fmaxf(mx[r], s);
      }
    }
#pragma unroll
    for (int r = 0; r < 4; r++)
#pragma unroll
      for (int m = 1; m < 16; m <<= 1) mx[r] = fmaxf(mx[r], __shfl_xor(mx[r], m, 64));
    float sum[4] = {0.f, 0.f, 0.f, 0.f};
#pragma unroll
    for (int t = 0; t < 13; t++)
#pragma unroll
      for (int r = 0; r < 4; r++) {
        float p = __expf(acc[t][r] - mx[r]);
        acc[t][r] = p;
        sum[r] += p;
      }
#pragma unroll
    for (int r = 0; r < 4; r++) {
#pragma unroll
      for (int m = 1; m < 16; m <<= 1) sum[r] += __shfl_xor(sum[r], m, 64);
      sum[r] = 1.0f / sum[r];
    }
    // P -> LDS (bf16)
#pragma unroll
    for (int t = 0; t < 13; t++) {
      int col = t * 16 + r16;
#pragma unroll
      for (int r = 0; r < 4; r++)
        Ps[w][(q4 * 4 + r) * PST + col] = f2bf(acc[t][r] * sum[r]);
    }
    // PV: 7 k-tiles of 32
    f32x4 o0 = z, o1 = z;
#pragma unroll
    for (int t = 0; t < 7; t++) {
      short8 ap = *(const short8*)(&Ps[w][r16 * PST + t * 32 + q4 * 8]);
      short8 b0 = *(const short8*)(&Vt[r16 * VST + t * 32 + q4 * 8]);
      short8 b1 = *(const short8*)(&Vt[(16 + r16) * VST + t * 32 + q4 * 8]);
      o0 = mfma16(ap, b0, o0);
      o1 = mfma16(ap, b1, o1);
    }
    // write O (bf16) to attnout[b][n][h*32+d]
#pragma unroll
    for (int r = 0; r < 4; r++) {
      int grow = si * 16 + q4 * 4 + r;
      if (grow < 196) {
        u16* op = ao + ((size_t)(b * 196 + grow)) * 768 + h * 32;
        op[r16] = f2bf(o0[r]);
        op[16 + r16] = f2bf(o1[r]);
      }
    }
  }
}

// ---------------------------------------------------------------------------
extern "C" void kernel_launch(void* const* d_in, const int* in_sizes, int n_in,
                              void* d_out, int out_size, void* d_ws, size_t ws_size,
                              hipStream_t stream) {
  const float* x = (const float*)d_in[0];
  const float* qkv_w = (const float*)d_in[1];
  const float* qkv_b = (const float*)d_in[2];
  const float* proj_w = (const float*)d_in[3];
  const float* proj_b = (const float*)d_in[4];
  const float* cpb_w1 = (const float*)d_in[5];
  const float* cpb_b1 = (const float*)d_in[6];
  const float* cpb_w2 = (const float*)d_in[7];
  const float* cpb_b2 = (const float*)d_in[8];
  float* out = (float*)d_out;

  char* ws = (char*)d_ws;
  size_t o = 0;
  auto alloc = [&](size_t sz) {
    size_t r = o;
    o = (o + sz + 255) & ~(size_t)255;
    return r;
  };
  const size_t ME = (size_t)25088 * 768;  // elems per [B,N,DIM]-sized tensor
  u16* x_bf = (u16*)(ws + alloc(ME * 2));           // also aliased as attnout
  u16* wq_t = (u16*)(ws + alloc((size_t)2304 * 768 * 2));
  u16* wp_t = (u16*)(ws + alloc((size_t)768 * 768 * 2));
  u16* qkv_s = (u16*)(ws + alloc(3 * ME * 2));      // [25088][2304] bf16
  float* btab = (float*)(ws + alloc((size_t)729 * 24 * 4));   // also OOB-read pad
  float* bexp = (float*)(ws + alloc((size_t)24 * 196 * 208 * 4));
  u16* ao = x_bf;  // alias: x_bf dead after qkv GEMM

  cvt_x_k<<<18816, 256, 0, stream>>>(x, x_bf);
  cvt_wt_k<<<6912, 256, 0, stream>>>(qkv_w, wq_t, 2304);
  cvt_wt_k<<<2304, 256, 0, stream>>>(proj_w, wp_t, 768);
  bias_mlp_k<<<729, 64, 0, stream>>>(cpb_w1, cpb_b1, cpb_w2, cpb_b2, btab);
  bias_expand_k<<<3822, 256, 0, stream>>>(btab, bexp);
  gemm_k<0><<<3528, 256, 0, stream>>>(x_bf, wq_t, qkv_b, nullptr, qkv_s,
                                      2304, 768, 18);
  attn_k<<<3072, 256, 0, stream>>>(qkv_s, bexp, ao);
  gemm_k<1><<<1176, 256, 0, stream>>>(ao, wp_t, proj_b, out, nullptr,
                                      768, 768, 6);
}